// Round 9
// baseline (597.630 us; speedup 1.0000x reference)
//
#include <hip/hip_runtime.h>

#define NN     1024
#define IN_D   256
#define OUT_D  256
#define BN     4               // n-rows per block; grid = 256 = 1 block/CU
#define NI2    (IN_D / 2)      // 128 ii-pairs
#define NG     8               // K-groups (tid>>7), 32 i's each
#define JPG    (NI2 / NG)      // 16 ii-pairs per group
#define OSLOTS (OUT_D / 2)     // 128; thread owns o = oslot and oslot+128

typedef float v2f __attribute__((ext_vector_type(2)));
typedef float v4f __attribute__((ext_vector_type(4)));

#define WLR_BYTES   (sizeof(float4) * NI2 * OUT_D)   // 512 KB
#define SINK_FLOATS (256 * 1024)                     // one float per thread
#define ABL_BYTES   (WLR_BYTES + 4 * SINK_FLOATS * sizeof(float))

__global__ __launch_bounds__(256) void fz_prep(
    const float* __restrict__ wb, const float* __restrict__ wa,
    const float* __restrict__ wc, float4* __restrict__ wlr2) {
    int t = blockIdx.x * 256 + threadIdx.x;        // 0 .. NI2*OUT-1
    int ii2 = t >> 8;
    int o   = t & (OUT_D - 1);
    int i0  = (2 * ii2) * OUT_D + o;
    int i1  = i0 + OUT_D;
    float4 w;
    w.x = wb[i0] - fmaxf(wa[i0], 0.0f);
    w.y = wb[i0] + fmaxf(wc[i0], 0.0f);
    w.z = wb[i1] - fmaxf(wa[i1], 0.0f);
    w.w = wb[i1] + fmaxf(wc[i1], 0.0f);
    wlr2[t] = w;
}

__device__ __forceinline__ void fz_tri(float a, float b, float wl, float wr,
                                       float& aL, float& aR) {
    // invariants: b >= a (hr >= hl), wr > 0
    float x  = a * wl;
    float y  = b * wl;
    float zl = a * wr;
    float zr = b * wr;
    aL += fminf(fminf(x, y), zl);                  // v_min3_f32 + add
    aR += fmaxf(fmaxf(x, y), zr);                  // v_max3_f32 + add
}

// MODE: 0=full, 1=noW (opaque consts), 2=noLDS (opaque consts), 3=loads-only
template <int MODE, int REPS, bool WRITE_OUT, bool RAWW>
__global__ __launch_bounds__(1024) void fz_abl(
    const float* __restrict__ hl, const float* __restrict__ hr,
    const float* __restrict__ wb, const float* __restrict__ wa,
    const float* __restrict__ wc, const float4* __restrict__ wlr2,
    const float* __restrict__ bb, const float* __restrict__ ba,
    const float* __restrict__ bc,
    float* __restrict__ out, float* __restrict__ sinkbuf) {
    __shared__ __align__(16) v2f ab[BN][IN_D];            // 8 KB {hl,hr}
    __shared__ __align__(16) v2f pl[NG][BN][2][OSLOTS];   // 64 KB partials

    const int tid   = threadIdx.x;
    const int oslot = tid & (OSLOTS - 1);
    const int g     = tid >> 7;
    const int n0    = blockIdx.x * BN;

    // stage BN rows of {hl,hr}: one (row, ii) per thread, coalesced
    {
        int row = tid >> 8;
        int ii  = tid & (IN_D - 1);
        v2f v; v.x = hl[(n0 + row) * IN_D + ii];
        v.y = hr[(n0 + row) * IN_D + ii];
        ab[row][ii] = v;
    }
    __syncthreads();

    // opaque constants (only materialized for ablation modes)
    float oz0 = 1.0f, oz1 = 1.0f, oz2 = 1.0f, oz3 = 1.0f,
          oz4 = 1.0f, oz5 = 1.0f, oz6 = 1.0f, oz7 = 1.0f;
    if (MODE == 1 || MODE == 2) {
        asm volatile("v_mov_b32 %0, 0x3e000000" : "=v"(oz0));
        asm volatile("v_mov_b32 %0, 0x3e800000" : "=v"(oz1));
        asm volatile("v_mov_b32 %0, 0x3ec00000" : "=v"(oz2));
        asm volatile("v_mov_b32 %0, 0x3f000000" : "=v"(oz3));
        asm volatile("v_mov_b32 %0, 0x3f200000" : "=v"(oz4));
        asm volatile("v_mov_b32 %0, 0x3f400000" : "=v"(oz5));
        asm volatile("v_mov_b32 %0, 0x3f600000" : "=v"(oz6));
        asm volatile("v_mov_b32 %0, 0x3f800000" : "=v"(oz7));
    }
    int jit = 0;
    if (REPS > 1) asm volatile("v_mov_b32 %0, 0" : "=v"(jit)); // opaque 0

    const int j0 = g * JPG;

    float accL[BN][2], accR[BN][2];
    float sink = 0.0f;

#pragma unroll 1
    for (int rep = 0; rep < REPS; ++rep) {
        const int jb = j0 + jit * rep;         // == j0 at runtime
#pragma unroll
        for (int t = 0; t < BN; ++t) {
            accL[t][0] = 0.0f; accL[t][1] = 0.0f;
            accR[t][0] = 0.0f; accR[t][1] = 0.0f;
        }

        const float4* wp0 = wlr2 + (size_t)jb * OUT_D + oslot;
        const float4* wp1 = wp0 + OSLOTS;

        auto raw_w = [&](int j, float4& w0, float4& w1) {
            int base = (jb + j) * 2 * OUT_D + oslot;
            float b00 = wb[base], a00 = wa[base], c00 = wc[base];
            float b10 = wb[base + OUT_D], a10 = wa[base + OUT_D], c10 = wc[base + OUT_D];
            w0.x = b00 - fmaxf(a00, 0.0f); w0.y = b00 + fmaxf(c00, 0.0f);
            w0.z = b10 - fmaxf(a10, 0.0f); w0.w = b10 + fmaxf(c10, 0.0f);
            int b1 = base + OSLOTS;
            float b01 = wb[b1], a01 = wa[b1], c01 = wc[b1];
            float b11 = wb[b1 + OUT_D], a11 = wa[b1 + OUT_D], c11 = wc[b1 + OUT_D];
            w1.x = b01 - fmaxf(a01, 0.0f); w1.y = b01 + fmaxf(c01, 0.0f);
            w1.z = b11 - fmaxf(a11, 0.0f); w1.w = b11 + fmaxf(c11, 0.0f);
        };

        // h-stream registers
        v4f a4c[BN], a4n[BN];
        if (MODE != 2) {
#pragma unroll
            for (int t = 0; t < BN; ++t)
                a4c[t] = *reinterpret_cast<const v4f*>(&ab[t][jb * 2]);
        } else {
#pragma unroll
            for (int t = 0; t < BN; ++t) {
                a4c[t].x = oz0 + t; a4c[t].y = oz1 + t;
                a4c[t].z = oz2 + t; a4c[t].w = oz3 + t;
            }
        }

        // depth-2 W double-buffer (R7 structure)
        float4 wd0[2], wd1[2];
        if (MODE == 0 || MODE == 3) {
            if (RAWW) { raw_w(0, wd0[0], wd1[0]); raw_w(1, wd0[1], wd1[1]); }
            else {
                wd0[0] = wp0[0];                 wd1[0] = wp1[0];
                wd0[1] = wp0[(size_t)1 * OUT_D]; wd1[1] = wp1[(size_t)1 * OUT_D];
            }
        }

#pragma unroll
        for (int j = 0; j < JPG; ++j) {
            float4 w0, w1;
            if (MODE == 0 || MODE == 3) {
                w0 = wd0[j & 1]; w1 = wd1[j & 1];
                if (j + 2 < JPG) {
                    if (RAWW) raw_w(j + 2, wd0[j & 1], wd1[j & 1]);
                    else {
                        wd0[j & 1] = wp0[(size_t)(j + 2) * OUT_D];
                        wd1[j & 1] = wp1[(size_t)(j + 2) * OUT_D];
                    }
                }
            } else {
                w0.x = oz0; w0.y = oz1; w0.z = oz2; w0.w = oz3;
                w1.x = oz4; w1.y = oz5; w1.z = oz6; w1.w = oz7;
            }
            if (MODE != 2) {
                if (j + 1 < JPG) {
                    const int iin = (jb + j + 1) * 2;
#pragma unroll
                    for (int t = 0; t < BN; ++t)
                        a4n[t] = *reinterpret_cast<const v4f*>(&ab[t][iin]);
                }
            }
            if (MODE == 3) {
                // loads-only: consume every loaded component cheaply
                accL[0][0] += (w0.x + w0.y) + (w0.z + w0.w);
                accL[1][0] += (w1.x + w1.y) + (w1.z + w1.w);
#pragma unroll
                for (int t = 0; t < BN; ++t)
                    accR[t][0] += (a4c[t].x + a4c[t].y) + (a4c[t].z + a4c[t].w);
            } else {
#pragma unroll
                for (int t = 0; t < BN; ++t) {
                    v4f a4 = a4c[t];
                    fz_tri(a4.x, a4.y, w0.x, w0.y, accL[t][0], accR[t][0]);
                    fz_tri(a4.z, a4.w, w0.z, w0.w, accL[t][0], accR[t][0]);
                    fz_tri(a4.x, a4.y, w1.x, w1.y, accL[t][1], accR[t][1]);
                    fz_tri(a4.z, a4.w, w1.z, w1.w, accL[t][1], accR[t][1]);
                }
            }
            if (MODE != 2) {
#pragma unroll
                for (int t = 0; t < BN; ++t) a4c[t] = a4n[t];
            }
        }
        sink += accL[0][0] + accR[0][0] + accL[1][0] + accR[1][1]
              + accL[2][1] + accR[2][0] + accL[3][1] + accR[3][1];
    }

    if (WRITE_OUT) {
#pragma unroll
        for (int t = 0; t < BN; ++t) {
            v2f p0; p0.x = accL[t][0]; p0.y = accR[t][0];
            v2f p1; p1.x = accL[t][1]; p1.y = accR[t][1];
            pl[g][t][0][oslot] = p0;
            pl[g][t][1][oslot] = p1;
        }
        __syncthreads();
        const int row  = g & 3;
        const int half = g >> 2;
        const int o    = oslot + half * OSLOTS;
        v2f sv = (v2f)(0.0f);
#pragma unroll
        for (int gg = 0; gg < NG; ++gg) sv += pl[gg][row][half][oslot];
        float bl = bb[o] - fmaxf(ba[o], 0.0f);
        float br = bb[o] + fmaxf(bc[o], 0.0f);
        size_t rl = (size_t)(n0 + row) * OUT_D + o;
        out[rl]                      = sv.x + bl;
        out[(size_t)NN * OUT_D + rl] = sv.y + br;
    } else {
        pl[g][0][0][oslot].x = sink;   // keep pl resident (same LDS footprint)
        __syncthreads();
        float extra = pl[(g + 1) & 7][0][0][oslot].x;
        sinkbuf[(size_t)blockIdx.x * 1024 + tid] = sink + extra;
    }
}

extern "C" void kernel_launch(void* const* d_in, const int* in_sizes, int n_in,
                              void* d_out, int out_size, void* d_ws, size_t ws_size,
                              hipStream_t stream) {
    const float* hl = (const float*)d_in[0];
    const float* hr = (const float*)d_in[1];
    const float* wb = (const float*)d_in[2];
    const float* wa = (const float*)d_in[3];
    const float* wc = (const float*)d_in[4];
    const float* bb = (const float*)d_in[5];
    const float* ba = (const float*)d_in[6];
    const float* bc = (const float*)d_in[7];
    float* out = (float*)d_out;

    dim3 grid(NN / BN);

    if (ws_size >= WLR_BYTES) {
        float4* wlr2 = (float4*)d_ws;
        fz_prep<<<(NI2 * OUT_D) / 256, 256, 0, stream>>>(wb, wa, wc, wlr2);
        if (ws_size >= ABL_BYTES) {
            float* s = (float*)((char*)d_ws + WLR_BYTES);
            fz_abl<0, 4, false, false><<<grid, 1024, 0, stream>>>(
                hl, hr, wb, wa, wc, wlr2, bb, ba, bc, nullptr, s + 0 * SINK_FLOATS);
            fz_abl<1, 4, false, false><<<grid, 1024, 0, stream>>>(
                hl, hr, wb, wa, wc, wlr2, bb, ba, bc, nullptr, s + 1 * SINK_FLOATS);
            fz_abl<2, 4, false, false><<<grid, 1024, 0, stream>>>(
                hl, hr, wb, wa, wc, wlr2, bb, ba, bc, nullptr, s + 2 * SINK_FLOATS);
            fz_abl<3, 4, false, false><<<grid, 1024, 0, stream>>>(
                hl, hr, wb, wa, wc, wlr2, bb, ba, bc, nullptr, s + 3 * SINK_FLOATS);
        }
        fz_abl<0, 1, true, false><<<grid, 1024, 0, stream>>>(
            hl, hr, wb, wa, wc, wlr2, bb, ba, bc, out, nullptr);
    } else {
        fz_abl<0, 1, true, true><<<grid, 1024, 0, stream>>>(
            hl, hr, wb, wa, wc, nullptr, bb, ba, bc, out, nullptr);
    }
}

// Round 10
// 32.472 us; speedup vs baseline: 18.4047x; 18.4047x over previous
//
#include <hip/hip_runtime.h>
#include <stdint.h>

#define NN     1024
#define IN_D   256
#define OUT_D  256
#define RPB    2                   // rows per block; grid = NN/RPB = 512 = 2 blocks/CU
#define NPAIRS (IN_D / 2)          // 128 i-pairs
#define CP     8                   // i-pairs per chunk (16 i)
#define NCHUNK (NPAIRS / CP)       // 16 chunks

typedef float v2f __attribute__((ext_vector_type(2)));
typedef float v4f __attribute__((ext_vector_type(4)));

// ws: float4 wlr2[pair*OUT+o] = {wl(2p,o), wr(2p,o), wl(2p+1,o), wr(2p+1,o)}
#define WLR_BYTES (sizeof(float4) * NPAIRS * OUT_D)   // 512 KB

__global__ __launch_bounds__(256) void fz_prep(
    const float* __restrict__ wb, const float* __restrict__ wa,
    const float* __restrict__ wc, float4* __restrict__ wlr2) {
    int t = blockIdx.x * 256 + threadIdx.x;        // 0 .. NPAIRS*OUT-1
    int pr = t >> 8;
    int o  = t & (OUT_D - 1);
    int i0 = (2 * pr) * OUT_D + o;
    int i1 = i0 + OUT_D;
    float4 w;
    w.x = wb[i0] - fmaxf(wa[i0], 0.0f);
    w.y = wb[i0] + fmaxf(wc[i0], 0.0f);
    w.z = wb[i1] - fmaxf(wa[i1], 0.0f);
    w.w = wb[i1] + fmaxf(wc[i1], 0.0f);
    wlr2[t] = w;
}

__device__ __forceinline__ void fz_tri(float a, float b, float wl, float wr,
                                       float& aL, float& aR) {
    // invariants: b >= a (hr >= hl), wr > 0
    //   min(p1..p4) = min3(a*wl, b*wl, a*wr); max(p1..p4) = max3(a*wl, b*wl, b*wr)
    float x  = a * wl;
    float y  = b * wl;
    float zl = a * wr;
    float zr = b * wr;
    aL += fminf(fminf(x, y), zl);                  // v_min3_f32 + add
    aR += fmaxf(fmaxf(x, y), zr);                  // v_max3_f32 + add
}

__global__ __launch_bounds__(256) void fz_main(
    const float* __restrict__ hl, const float* __restrict__ hr,
    const float4* __restrict__ wlr2,
    const float* __restrict__ bb, const float* __restrict__ ba,
    const float* __restrict__ bc, float* __restrict__ out) {
    __shared__ __align__(16) v4f wbuf[2][CP][OUT_D];   // 64 KB W double-buffer
    __shared__ __align__(16) v2f ab[RPB][IN_D];        // 4 KB {hl,hr} pairs

    const int tid = threadIdx.x;
    const int o   = tid;                           // this thread's o-column
    const int n0  = blockIdx.x * RPB;

    // ---- prologue: stage RPB rows of {hl,hr} interleaved (float4 loads) ----
    if (tid < RPB * (IN_D / 4)) {                  // 128 active threads
        int row = tid >> 6;
        int c4  = tid & 63;
        v4f A = *reinterpret_cast<const v4f*>(&hl[(n0 + row) * IN_D + c4 * 4]);
        v4f B = *reinterpret_cast<const v4f*>(&hr[(n0 + row) * IN_D + c4 * 4]);
        v2f* dst = &ab[row][c4 * 4];
        v2f t0; t0.x = A.x; t0.y = B.x; dst[0] = t0;
        v2f t1; t1.x = A.y; t1.y = B.y; dst[1] = t1;
        v2f t2; t2.x = A.z; t2.y = B.z; dst[2] = t2;
        v2f t3; t3.x = A.w; t3.y = B.w; dst[3] = t3;
    }

    // ---- stage chunk 0 into wbuf[0] (async direct-to-LDS, 16 B/lane) ----
#pragma unroll
    for (int p = 0; p < CP; ++p) {
        const float4* g = &wlr2[(size_t)p * OUT_D + o];
        __builtin_amdgcn_global_load_lds(
            (const __attribute__((address_space(1))) void*)g,
            (__attribute__((address_space(3))) void*)&wbuf[0][p][o], 16, 0, 0);
    }
    __syncthreads();                               // drains gll chunk0 + ab writes

    float aL0 = 0.0f, aR0 = 0.0f, aL1 = 0.0f, aR1 = 0.0f;

#pragma unroll 1
    for (int c = 0; c < NCHUNK; ++c) {
        // issue next chunk's async loads first (max overlap window)
        if (c + 1 < NCHUNK) {
            v4f (*nbuf)[OUT_D] = wbuf[(c + 1) & 1];
#pragma unroll
            for (int p = 0; p < CP; ++p) {
                const float4* g = &wlr2[(size_t)((c + 1) * CP + p) * OUT_D + o];
                __builtin_amdgcn_global_load_lds(
                    (const __attribute__((address_space(1))) void*)g,
                    (__attribute__((address_space(3))) void*)&nbuf[p][o], 16, 0, 0);
            }
        }
        // compute current chunk (named scalar accs — no register arrays)
        v4f (*cbuf)[OUT_D] = wbuf[c & 1];
#pragma unroll
        for (int p = 0; p < CP; ++p) {
            v4f w = cbuf[p][o];                    // lane-varying ds_read_b128
            const int k = (c * CP + p) * 2;
            v4f h0 = *reinterpret_cast<const v4f*>(&ab[0][k]);   // broadcast
            v4f h1 = *reinterpret_cast<const v4f*>(&ab[1][k]);   // broadcast
            fz_tri(h0.x, h0.y, w.x, w.y, aL0, aR0);   // row0, i_a
            fz_tri(h0.z, h0.w, w.z, w.w, aL0, aR0);   // row0, i_b
            fz_tri(h1.x, h1.y, w.x, w.y, aL1, aR1);   // row1, i_a
            fz_tri(h1.z, h1.w, w.z, w.w, aL1, aR1);   // row1, i_b
        }
        __syncthreads();   // vmcnt drain of (c+1) gll — issued 1 full chunk ago
    }

    // ---- epilogue: bias + direct stores (no reduction needed) ----
    float bl = bb[o] - fmaxf(ba[o], 0.0f);
    float br = bb[o] + fmaxf(bc[o], 0.0f);
    size_t r0 = (size_t)n0 * OUT_D + o;
    out[r0]                              = aL0 + bl;
    out[r0 + OUT_D]                      = aL1 + bl;
    out[(size_t)NN * OUT_D + r0]         = aR0 + br;
    out[(size_t)NN * OUT_D + r0 + OUT_D] = aR1 + br;
}

// correctness-only fallback if ws is too small (never expected to run)
__global__ __launch_bounds__(256) void fz_fallback(
    const float* __restrict__ hl, const float* __restrict__ hr,
    const float* __restrict__ wb, const float* __restrict__ wa,
    const float* __restrict__ wc,
    const float* __restrict__ bb, const float* __restrict__ ba,
    const float* __restrict__ bc, float* __restrict__ out) {
    __shared__ __align__(16) v2f ab[RPB][IN_D];
    const int tid = threadIdx.x;
    const int o   = tid;
    const int n0  = blockIdx.x * RPB;
    if (tid < RPB * (IN_D / 4)) {
        int row = tid >> 6;
        int c4  = tid & 63;
        v4f A = *reinterpret_cast<const v4f*>(&hl[(n0 + row) * IN_D + c4 * 4]);
        v4f B = *reinterpret_cast<const v4f*>(&hr[(n0 + row) * IN_D + c4 * 4]);
        v2f* dst = &ab[row][c4 * 4];
        v2f t0; t0.x = A.x; t0.y = B.x; dst[0] = t0;
        v2f t1; t1.x = A.y; t1.y = B.y; dst[1] = t1;
        v2f t2; t2.x = A.z; t2.y = B.z; dst[2] = t2;
        v2f t3; t3.x = A.w; t3.y = B.w; dst[3] = t3;
    }
    __syncthreads();
    float aL0 = 0.0f, aR0 = 0.0f, aL1 = 0.0f, aR1 = 0.0f;
    for (int i = 0; i < IN_D; ++i) {
        int wi = i * OUT_D + o;
        float wl = wb[wi] - fmaxf(wa[wi], 0.0f);
        float wr = wb[wi] + fmaxf(wc[wi], 0.0f);
        v2f h0 = ab[0][i], h1 = ab[1][i];
        fz_tri(h0.x, h0.y, wl, wr, aL0, aR0);
        fz_tri(h1.x, h1.y, wl, wr, aL1, aR1);
    }
    float bl = bb[o] - fmaxf(ba[o], 0.0f);
    float br = bb[o] + fmaxf(bc[o], 0.0f);
    size_t r0 = (size_t)n0 * OUT_D + o;
    out[r0]                              = aL0 + bl;
    out[r0 + OUT_D]                      = aL1 + bl;
    out[(size_t)NN * OUT_D + r0]         = aR0 + br;
    out[(size_t)NN * OUT_D + r0 + OUT_D] = aR1 + br;
}

extern "C" void kernel_launch(void* const* d_in, const int* in_sizes, int n_in,
                              void* d_out, int out_size, void* d_ws, size_t ws_size,
                              hipStream_t stream) {
    const float* hl = (const float*)d_in[0];
    const float* hr = (const float*)d_in[1];
    const float* wb = (const float*)d_in[2];
    const float* wa = (const float*)d_in[3];
    const float* wc = (const float*)d_in[4];
    const float* bb = (const float*)d_in[5];
    const float* ba = (const float*)d_in[6];
    const float* bc = (const float*)d_in[7];
    float* out = (float*)d_out;

    if (ws_size >= WLR_BYTES) {
        float4* wlr2 = (float4*)d_ws;
        fz_prep<<<(NPAIRS * OUT_D) / 256, 256, 0, stream>>>(wb, wa, wc, wlr2);
        fz_main<<<NN / RPB, 256, 0, stream>>>(hl, hr, wlr2, bb, ba, bc, out);
    } else {
        fz_fallback<<<NN / RPB, 256, 0, stream>>>(hl, hr, wb, wa, wc,
                                                  bb, ba, bc, out);
    }
}